// Round 2
// baseline (186.823 us; speedup 1.0000x reference)
//
#include <hip/hip_runtime.h>

// Kill FMA contraction globally: we must match numpy/XLA's separate mul+add
// rounding bit-for-bit, or borderline mask bits flip and the compaction shifts.
#pragma clang fp contract(off)

namespace {

constexpr int S = 64;
// linspace(0,1,64): t_i = i * fl(1/63). fl(63*fl(1/63)) == 1.0f exactly.
constexpr float DELTA = 1.0f / 63.0f;

__device__ __forceinline__ void ray_nearfar(
    float ox, float oy, float oz,
    float dx, float dy, float dz,
    float R, float& nr, float& fr) {
  float ix = 1.0f / ((dx == 0.0f) ? 1e-6f : dx);
  float iy = 1.0f / ((dy == 0.0f) ? 1e-6f : dy);
  float iz = 1.0f / ((dz == 0.0f) ? 1e-6f : dz);
  float mR = -R;
  float ax = (mR - ox) * ix, bx = (R - ox) * ix;
  float ay = (mR - oy) * iy, by = (R - oy) * iy;
  float az = (mR - oz) * iz, bz = (R - oz) * iz;
  nr = fmaxf(fmaxf(fminf(ax, bx), fminf(ay, by)), fminf(az, bz));
  fr = fminf(fminf(fmaxf(ax, bx), fmaxf(ay, by)), fmaxf(az, bz));
}

// Kernel A: one thread per ray. Compute near/f + 64-bit validity mask, persist
// them (float4: nr, f, mask_lo, mask_hi). Exclusive scan of counts in-block.
__global__ __launch_bounds__(256) void k_count(
    const float* __restrict__ ro, const float* __restrict__ rd,
    const float* __restrict__ radii,
    float4* __restrict__ rayinfo,
    int* __restrict__ L, int* __restrict__ blockSums, int N) {
  int r = blockIdx.x * 256 + threadIdx.x;
  int cnt = 0;
  if (r < N) {
    float R = radii[0];
    float ox = ro[3 * r], oy = ro[3 * r + 1], oz = ro[3 * r + 2];
    float dx = rd[3 * r], dy = rd[3 * r + 1], dz = rd[3 * r + 2];
    float nr, fr;
    ray_nearfar(ox, oy, oz, dx, dy, dz, R, nr, fr);
    float f = fr - nr;
    unsigned lo = 0, hi = 0;
    for (int s = 0; s < S; ++s) {
      float dep = nr + f * ((float)s * DELTA);
      float sx = (ox + dx * dep) / R;
      float sy = (oy + dy * dep) / R;
      float sz = (oz + dz * dep) / R;
      float nm = sqrtf((sx * sx + sy * sy) + sz * sz);
      unsigned bit = (nm <= 1.0f) ? 1u : 0u;
      if (s < 32) lo |= bit << s; else hi |= bit << (s - 32);
      cnt += (int)bit;
    }
    rayinfo[r] = make_float4(nr, f, __uint_as_float(lo), __uint_as_float(hi));
  }
  __shared__ int sm[256];
  sm[threadIdx.x] = cnt;
  __syncthreads();
  for (int off = 1; off < 256; off <<= 1) {
    int t = (threadIdx.x >= off) ? sm[threadIdx.x - off] : 0;
    __syncthreads();
    sm[threadIdx.x] += t;
    __syncthreads();
  }
  if (r < N) L[r] = sm[threadIdx.x] - cnt;  // exclusive within block
  if (threadIdx.x == 255) blockSums[blockIdx.x] = sm[255];
}

// Kernel B: single block scans the (<=1024) block sums -> exclusive block
// offsets, total valid count (int to ws, float to d_out tail).
__global__ __launch_bounds__(1024) void k_scan(
    const int* __restrict__ blockSums, int* __restrict__ blockOff,
    int* __restrict__ total, float* __restrict__ out_nv, int nb) {
  __shared__ int sm[1024];
  int x = (threadIdx.x < nb) ? blockSums[threadIdx.x] : 0;
  sm[threadIdx.x] = x;
  __syncthreads();
  for (int off = 1; off < 1024; off <<= 1) {
    int t = (threadIdx.x >= off) ? sm[threadIdx.x - off] : 0;
    __syncthreads();
    sm[threadIdx.x] += t;
    __syncthreads();
  }
  if (threadIdx.x < nb) blockOff[threadIdx.x] = sm[threadIdx.x] - x;
  if (threadIdx.x == 1023) {
    *total = sm[1023];
    out_nv[0] = (float)sm[1023];
  }
}

// Kernel D: one wave per ray, lane = sample. All per-ray data is loaded via
// readfirstlane-uniform indices -> scalar (s_load) path, zero vector loads.
__global__ __launch_bounds__(256) void k_scatter(
    const float* __restrict__ ro, const float* __restrict__ rd,
    const float* __restrict__ radii,
    const float4* __restrict__ rayinfo,
    const int* __restrict__ L, const int* __restrict__ blockOff,
    const int* __restrict__ total,
    float* __restrict__ out, int N) {
  int s = threadIdx.x & 63;
  int r = blockIdx.x * 4 + (threadIdx.x >> 6);   // wave-uniform
  int ru = __builtin_amdgcn_readfirstlane(r);    // force SGPR -> s_load path

  float R = radii[0];
  float4 info = rayinfo[ru];
  float nr = info.x, f = info.y;
  unsigned long long msk =
      ((unsigned long long)__float_as_uint(info.w) << 32) |
      (unsigned long long)__float_as_uint(info.z);
  float ox = ro[3 * ru], oy = ro[3 * ru + 1], oz = ro[3 * ru + 2];
  float dx = rd[3 * ru], dy = rd[3 * ru + 1], dz = rd[3 * ru + 2];
  int Vr = L[ru] + blockOff[ru >> 8];  // global # of valid elems before ray
  int nv = *total;

  bool bit = (msk >> s) & 1ull;
  int below = __popcll(msk & ((1ull << s) - 1ull));

  float dep = nr + f * ((float)s * DELTA);
  float sx = (ox + dx * dep) / R;
  float sy = (oy + dy * dep) / R;
  float sz = (oz + dz * dep) / R;
  // deltas = diff(depth, prepend=near): replicate exactly.
  float prev = (s == 0) ? nr : (nr + f * ((float)(s - 1) * DELTA));
  float del = dep - prev;

  // valid -> compact front; invalid -> tail, both stable.
  int ray_base = ru * S;
  int dest = bit ? (Vr + below)
                 : (nv + (ray_base - Vr) + (s - below));

  int M = N * S;
  float* out_s  = out + M;       // samples_c [M,3]
  float* out_d  = out + 4 * M;   // depth_c   [M]
  float* out_dl = out + 5 * M;   // deltas_c  [M,1]
  float* out_b  = out + 6 * M;   // boundary  [M]
  out[dest] = (float)ru;
  out_s[3 * dest + 0] = sx;
  out_s[3 * dest + 1] = sy;
  out_s[3 * dest + 2] = sz;
  out_d[dest] = dep;
  out_dl[dest] = del;
  out_b[dest] = (bit && below == 0) ? 1.0f : 0.0f;
}

}  // namespace

extern "C" void kernel_launch(void* const* d_in, const int* in_sizes, int n_in,
                              void* d_out, int out_size, void* d_ws, size_t ws_size,
                              hipStream_t stream) {
  const float* ro = (const float*)d_in[0];
  const float* rd = (const float*)d_in[1];
  const float* radii = (const float*)d_in[2];
  int N = in_sizes[0] / 3;           // 262144
  int M = N * S;                     // 16777216
  int nbA = (N + 255) / 256;         // 1024

  float4* rayinfo = (float4*)d_ws;             // N float4 (16B aligned)
  int* wsI = (int*)(rayinfo + N);
  int* L = wsI;                      // N ints
  int* blockSums = wsI + N;          // nbA ints
  int* blockOff = blockSums + nbA;   // nbA ints
  int* total = blockOff + nbA;       // 1 int

  float* out = (float*)d_out;
  float* out_nv = out + (size_t)7 * (size_t)M;  // num_valid slot

  k_count<<<nbA, 256, 0, stream>>>(ro, rd, radii, rayinfo, L, blockSums, N);
  k_scan<<<1, 1024, 0, stream>>>(blockSums, blockOff, total, out_nv, nbA);
  k_scatter<<<N / 4, 256, 0, stream>>>(ro, rd, radii, rayinfo, L, blockOff,
                                       total, out, N);
}

// Round 3
// 156.230 us; speedup vs baseline: 1.1958x; 1.1958x over previous
//
#include <hip/hip_runtime.h>

// Kill FMA contraction globally: we must match numpy/XLA's separate mul+add
// rounding bit-for-bit, or borderline mask bits flip and the compaction shifts.
#pragma clang fp contract(off)

namespace {

constexpr int S = 64;
// linspace(0,1,64): t_i = i * fl(1/63). fl(63*fl(1/63)) == 1.0f exactly.
constexpr float DELTA = 1.0f / 63.0f;

constexpr int RPB = 16;                   // rays per staging block
constexpr int Q = RPB * S;                // 1024 samples per block
constexpr int LDSF = 7 * Q;               // 7 floats staged per sample
constexpr int LDSP = LDSF + (LDSF >> 5);  // +1 pad float per 32 -> conflict-free float4 gather

__device__ __forceinline__ int sw(int i) { return i + (i >> 5); }

__device__ __forceinline__ void ray_nearfar(
    float ox, float oy, float oz,
    float dx, float dy, float dz,
    float R, float& nr, float& fr) {
  float ix = 1.0f / ((dx == 0.0f) ? 1e-6f : dx);
  float iy = 1.0f / ((dy == 0.0f) ? 1e-6f : dy);
  float iz = 1.0f / ((dz == 0.0f) ? 1e-6f : dz);
  float mR = -R;
  float ax = (mR - ox) * ix, bx = (R - ox) * ix;
  float ay = (mR - oy) * iy, by = (R - oy) * iy;
  float az = (mR - oz) * iz, bz = (R - oz) * iz;
  nr = fmaxf(fmaxf(fminf(ax, bx), fminf(ay, by)), fminf(az, bz));
  fr = fminf(fminf(fmaxf(ax, bx), fmaxf(ay, by)), fmaxf(az, bz));
}

// Kernel A: one thread per ray. Compute near/f + 64-bit validity mask, persist
// them (float4: nr, f, mask_lo, mask_hi). Exclusive scan of counts in-block.
__global__ __launch_bounds__(256) void k_count(
    const float* __restrict__ ro, const float* __restrict__ rd,
    const float* __restrict__ radii,
    float4* __restrict__ rayinfo,
    int* __restrict__ L, int* __restrict__ blockSums, int N) {
  int r = blockIdx.x * 256 + threadIdx.x;
  int cnt = 0;
  if (r < N) {
    float R = radii[0];
    float ox = ro[3 * r], oy = ro[3 * r + 1], oz = ro[3 * r + 2];
    float dx = rd[3 * r], dy = rd[3 * r + 1], dz = rd[3 * r + 2];
    float nr, fr;
    ray_nearfar(ox, oy, oz, dx, dy, dz, R, nr, fr);
    float f = fr - nr;
    unsigned lo = 0, hi = 0;
    for (int s = 0; s < S; ++s) {
      float dep = nr + f * ((float)s * DELTA);
      float sx = (ox + dx * dep) / R;
      float sy = (oy + dy * dep) / R;
      float sz = (oz + dz * dep) / R;
      float nm = sqrtf((sx * sx + sy * sy) + sz * sz);
      unsigned bit = (nm <= 1.0f) ? 1u : 0u;
      if (s < 32) lo |= bit << s; else hi |= bit << (s - 32);
      cnt += (int)bit;
    }
    rayinfo[r] = make_float4(nr, f, __uint_as_float(lo), __uint_as_float(hi));
  }
  __shared__ int sm[256];
  sm[threadIdx.x] = cnt;
  __syncthreads();
  for (int off = 1; off < 256; off <<= 1) {
    int t = (threadIdx.x >= off) ? sm[threadIdx.x - off] : 0;
    __syncthreads();
    sm[threadIdx.x] += t;
    __syncthreads();
  }
  if (r < N) L[r] = sm[threadIdx.x] - cnt;  // exclusive within block
  if (threadIdx.x == 255) blockSums[blockIdx.x] = sm[255];
}

// Kernel B: single block scans the (<=1024) block sums -> exclusive block
// offsets, total valid count (int to ws, float to d_out tail).
__global__ __launch_bounds__(1024) void k_scan(
    const int* __restrict__ blockSums, int* __restrict__ blockOff,
    int* __restrict__ total, float* __restrict__ out_nv, int nb) {
  __shared__ int sm[1024];
  int x = (threadIdx.x < nb) ? blockSums[threadIdx.x] : 0;
  sm[threadIdx.x] = x;
  __syncthreads();
  for (int off = 1; off < 1024; off <<= 1) {
    int t = (threadIdx.x >= off) ? sm[threadIdx.x - off] : 0;
    __syncthreads();
    sm[threadIdx.x] += t;
    __syncthreads();
  }
  if (threadIdx.x < nb) blockOff[threadIdx.x] = sm[threadIdx.x] - x;
  if (threadIdx.x == 1023) {
    *total = sm[1023];
    out_nv[0] = (float)sm[1023];
  }
}

// Kernel C: 16 rays per block. Block-local stable partition into LDS, then
// stream out both contiguous output ranges per array with aligned float4
// stores (scalar fringe < 4 elems each side). XCD-chunked block swizzle keeps
// data-adjacent blocks on one XCD so boundary cachelines merge in L2.
__global__ __launch_bounds__(256) void k_stage(
    const float* __restrict__ ro, const float* __restrict__ rd,
    const float* __restrict__ radii,
    const float4* __restrict__ rayinfo,
    const int* __restrict__ L, const int* __restrict__ blockOff,
    const int* __restrict__ total,
    float* __restrict__ out, int N) {
  __shared__ float buf[LDSP];
  int nwg = gridDim.x;                 // divisible by 8 (16384)
  int chunk = nwg >> 3;
  int hw = blockIdx.x;
  int bid = (hw & 7) * chunk + (hw >> 3);
  int r0 = bid * RPB;
  int tid = threadIdx.x;
  int nv = *total;
  int V0 = L[r0] + blockOff[r0 >> 8];
  int rB = r0 + RPB;
  int VB = (rB >= N) ? nv : (L[rB] + blockOff[rB >> 8]);
  int cV = VB - V0;                    // valid samples in this block
  int TV = r0 * S - V0;                // invalid samples before this block

  // ---- compute + local stable partition into LDS ----
  int rloc = tid >> 4;                 // 16 threads per ray
  int r = r0 + rloc;
  int s0 = (tid & 15) * 4;             // 4 samples per thread
  float R = radii[0];
  float4 info = rayinfo[r];
  float nr = info.x, f = info.y;
  unsigned long long msk =
      ((unsigned long long)__float_as_uint(info.w) << 32) |
      (unsigned long long)__float_as_uint(info.z);
  float ox = ro[3 * r], oy = ro[3 * r + 1], oz = ro[3 * r + 2];
  float dx = rd[3 * r], dy = rd[3 * r + 1], dz = rd[3 * r + 2];
  int Vr = L[r] + blockOff[r >> 8];
  #pragma unroll
  for (int j = 0; j < 4; ++j) {
    int s = s0 + j;
    bool bit = (msk >> s) & 1ull;
    int below = __popcll(msk & ((1ull << s) - 1ull));
    float dep = nr + f * ((float)s * DELTA);
    float sx = (ox + dx * dep) / R;
    float sy = (oy + dy * dep) / R;
    float sz = (oz + dz * dep) / R;
    float prev = (s == 0) ? nr : (nr + f * ((float)(s - 1) * DELTA));
    float del = dep - prev;
    int l = bit ? (Vr - V0 + below)
                : (cV + (r * S - Vr) - TV + (s - below));
    buf[sw(l)] = (float)r;
    buf[sw(Q + 3 * l)] = sx;
    buf[sw(Q + 3 * l + 1)] = sy;
    buf[sw(Q + 3 * l + 2)] = sz;
    buf[sw(4 * Q + l)] = dep;
    buf[sw(5 * Q + l)] = del;
    buf[sw(6 * Q + l)] = (bit && below == 0) ? 1.0f : 0.0f;
  }
  __syncthreads();

  // ---- streaming write phase ----
  size_t M = (size_t)N * S;
  auto wr = [&](int lds0, size_t g0, int cnt) {
    int a0 = (int)((4 - (g0 & 3)) & 3);
    if (a0 > cnt) a0 = cnt;
    int na = (cnt - a0) & ~3;
    int a1 = a0 + na;
    for (int e = tid; e < a0; e += 256) out[g0 + e] = buf[sw(lds0 + e)];
    for (int e = a1 + tid; e < cnt; e += 256) out[g0 + e] = buf[sw(lds0 + e)];
    int n4 = na >> 2;
    for (int c = tid; c < n4; c += 256) {
      int l = lds0 + a0 + 4 * c;
      float4 v = make_float4(buf[sw(l)], buf[sw(l + 1)],
                             buf[sw(l + 2)], buf[sw(l + 3)]);
      *reinterpret_cast<float4*>(out + (g0 + (size_t)a0 + 4 * (size_t)c)) = v;
    }
  };
  size_t tail0 = (size_t)nv + (size_t)TV;
  int cT = Q - cV;
  // ridx
  wr(0, (size_t)V0, cV);
  wr(cV, tail0, cT);
  // samples [M,3]
  wr(Q, M + 3 * (size_t)V0, 3 * cV);
  wr(Q + 3 * cV, M + 3 * tail0, 3 * cT);
  // depth
  wr(4 * Q, 4 * M + (size_t)V0, cV);
  wr(4 * Q + cV, 4 * M + tail0, cT);
  // deltas
  wr(5 * Q, 5 * M + (size_t)V0, cV);
  wr(5 * Q + cV, 5 * M + tail0, cT);
  // boundary
  wr(6 * Q, 6 * M + (size_t)V0, cV);
  wr(6 * Q + cV, 6 * M + tail0, cT);
}

}  // namespace

extern "C" void kernel_launch(void* const* d_in, const int* in_sizes, int n_in,
                              void* d_out, int out_size, void* d_ws, size_t ws_size,
                              hipStream_t stream) {
  const float* ro = (const float*)d_in[0];
  const float* rd = (const float*)d_in[1];
  const float* radii = (const float*)d_in[2];
  int N = in_sizes[0] / 3;           // 262144
  int M = N * S;                     // 16777216
  int nbA = (N + 255) / 256;         // 1024

  float4* rayinfo = (float4*)d_ws;             // N float4 (16B aligned)
  int* wsI = (int*)(rayinfo + N);
  int* L = wsI;                      // N ints
  int* blockSums = wsI + N;          // nbA ints
  int* blockOff = blockSums + nbA;   // nbA ints
  int* total = blockOff + nbA;       // 1 int

  float* out = (float*)d_out;
  float* out_nv = out + (size_t)7 * (size_t)M;  // num_valid slot

  k_count<<<nbA, 256, 0, stream>>>(ro, rd, radii, rayinfo, L, blockSums, N);
  k_scan<<<1, 1024, 0, stream>>>(blockSums, blockOff, total, out_nv, nbA);
  k_stage<<<N / RPB, 256, 0, stream>>>(ro, rd, radii, rayinfo, L, blockOff,
                                       total, out, N);
}

// Round 4
// 140.381 us; speedup vs baseline: 1.3308x; 1.1129x over previous
//
#include <hip/hip_runtime.h>

// Kill FMA contraction globally: we must match numpy/XLA's separate mul+add
// rounding bit-for-bit, or borderline mask bits flip and the compaction shifts.
#pragma clang fp contract(off)

namespace {

constexpr int S = 64;
// linspace(0,1,64): t_i = i * fl(1/63). fl(63*fl(1/63)) == 1.0f exactly.
constexpr float DELTA = 1.0f / 63.0f;

constexpr int RPB = 16;                   // rays per staging block
constexpr int Q = RPB * S;                // 1024 samples per block
// Per-array LDS slots (+16 slack for mod-4 congruence padding):
// ridx Q, samples 3Q, depth Q, deltas Q, boundary Q
constexpr int LDSF = 7 * Q + 5 * 16;      // 7248 floats = 29.0 KB

__device__ __forceinline__ void ray_nearfar(
    float ox, float oy, float oz,
    float dx, float dy, float dz,
    float R, float& nr, float& fr) {
  float ix = 1.0f / ((dx == 0.0f) ? 1e-6f : dx);
  float iy = 1.0f / ((dy == 0.0f) ? 1e-6f : dy);
  float iz = 1.0f / ((dz == 0.0f) ? 1e-6f : dz);
  float mR = -R;
  float ax = (mR - ox) * ix, bx = (R - ox) * ix;
  float ay = (mR - oy) * iy, by = (R - oy) * iy;
  float az = (mR - oz) * iz, bz = (R - oz) * iz;
  nr = fmaxf(fmaxf(fminf(ax, bx), fminf(ay, by)), fminf(az, bz));
  fr = fminf(fminf(fmaxf(ax, bx), fmaxf(ay, by)), fmaxf(az, bz));
}

// Kernel A: one thread per ray. Compute near/f + 64-bit validity mask, persist
// them (float4: nr, f, mask_lo, mask_hi). Exclusive scan of counts in-block.
__global__ __launch_bounds__(256) void k_count(
    const float* __restrict__ ro, const float* __restrict__ rd,
    const float* __restrict__ radii,
    float4* __restrict__ rayinfo,
    int* __restrict__ L, int* __restrict__ blockSums, int N) {
  int r = blockIdx.x * 256 + threadIdx.x;
  int cnt = 0;
  if (r < N) {
    float R = radii[0];
    float ox = ro[3 * r], oy = ro[3 * r + 1], oz = ro[3 * r + 2];
    float dx = rd[3 * r], dy = rd[3 * r + 1], dz = rd[3 * r + 2];
    float nr, fr;
    ray_nearfar(ox, oy, oz, dx, dy, dz, R, nr, fr);
    float f = fr - nr;
    unsigned lo = 0, hi = 0;
    for (int s = 0; s < S; ++s) {
      float dep = nr + f * ((float)s * DELTA);
      float sx = (ox + dx * dep) / R;
      float sy = (oy + dy * dep) / R;
      float sz = (oz + dz * dep) / R;
      float nm = sqrtf((sx * sx + sy * sy) + sz * sz);
      unsigned bit = (nm <= 1.0f) ? 1u : 0u;
      if (s < 32) lo |= bit << s; else hi |= bit << (s - 32);
      cnt += (int)bit;
    }
    rayinfo[r] = make_float4(nr, f, __uint_as_float(lo), __uint_as_float(hi));
  }
  __shared__ int sm[256];
  sm[threadIdx.x] = cnt;
  __syncthreads();
  for (int off = 1; off < 256; off <<= 1) {
    int t = (threadIdx.x >= off) ? sm[threadIdx.x - off] : 0;
    __syncthreads();
    sm[threadIdx.x] += t;
    __syncthreads();
  }
  if (r < N) L[r] = sm[threadIdx.x] - cnt;  // exclusive within block
  if (threadIdx.x == 255) blockSums[blockIdx.x] = sm[255];
}

// Kernel B: single block scans the (<=1024) block sums -> exclusive block
// offsets, total valid count (int to ws, float to d_out tail).
__global__ __launch_bounds__(1024) void k_scan(
    const int* __restrict__ blockSums, int* __restrict__ blockOff,
    int* __restrict__ total, float* __restrict__ out_nv, int nb) {
  __shared__ int sm[1024];
  int x = (threadIdx.x < nb) ? blockSums[threadIdx.x] : 0;
  sm[threadIdx.x] = x;
  __syncthreads();
  for (int off = 1; off < 1024; off <<= 1) {
    int t = (threadIdx.x >= off) ? sm[threadIdx.x - off] : 0;
    __syncthreads();
    sm[threadIdx.x] += t;
    __syncthreads();
  }
  if (threadIdx.x < nb) blockOff[threadIdx.x] = sm[threadIdx.x] - x;
  if (threadIdx.x == 1023) {
    *total = sm[1023];
    out_nv[0] = (float)sm[1023];
  }
}

// Kernel C: 16 rays per block. Block-local stable partition into LDS laid out
// congruent (mod 4 floats) with each run's global destination, then stream out
// with float4 ds_read_b128 -> aligned global_store_dwordx4. Fringes are <=3
// elems per run edge (single predicated store). XCD-chunked block swizzle.
__global__ __launch_bounds__(256) void k_stage(
    const float* __restrict__ ro, const float* __restrict__ rd,
    const float* __restrict__ radii,
    const float4* __restrict__ rayinfo,
    const int* __restrict__ L, const int* __restrict__ blockOff,
    const int* __restrict__ total,
    float* __restrict__ out, int N) {
  __shared__ __align__(16) float buf[LDSF];
  int nwg = gridDim.x;                 // divisible by 8 (16384)
  int chunk = nwg >> 3;
  int hw = blockIdx.x;
  int bid = (hw & 7) * chunk + (hw >> 3);
  int r0 = bid * RPB;
  int tid = threadIdx.x;
  int nv = *total;
  int V0 = L[r0] + blockOff[r0 >> 8];
  int rB = r0 + RPB;
  int VB = (rB >= N) ? nv : (L[rB] + blockOff[rB >> 8]);
  int cV = VB - V0;                    // valid samples in this block
  int cT = Q - cV;
  int TV = r0 * S - V0;                // invalid samples before this block
  size_t tail0 = (size_t)nv + (size_t)TV;
  int tmod = (int)(tail0 & 3);

  // ---- per-array LDS run bases, congruent mod 4 with global dests ----
  // scales: ridx 1, samples 3, depth 1, deltas 1, boundary 1
  int Sv[5], St[5];
  {
    int base = 0;
    #pragma unroll
    for (int a = 0; a < 5; ++a) {
      int k = (a == 1) ? 3 : 1;
      int vm = (k * V0) & 3;
      int tm2 = (k == 3) ? ((3 * (int)(tail0 & 3)) & 3) : tmod;
      Sv[a] = base + vm;
      St[a] = ((Sv[a] + k * cV + 3) & ~3) + tm2;
      base += k * Q + 16;
    }
  }

  // ---- compute + local stable partition into LDS ----
  int rloc = tid >> 4;                 // 16 threads per ray
  int r = r0 + rloc;
  float R = radii[0];
  float4 info = rayinfo[r];
  float nr = info.x, f = info.y;
  unsigned long long msk =
      ((unsigned long long)__float_as_uint(info.w) << 32) |
      (unsigned long long)__float_as_uint(info.z);
  float ox = ro[3 * r], oy = ro[3 * r + 1], oz = ro[3 * r + 2];
  float dx = rd[3 * r], dy = rd[3 * r + 1], dz = rd[3 * r + 2];
  int Vr = L[r] + blockOff[r >> 8];
  float fr = (float)r;
  #pragma unroll
  for (int j = 0; j < 4; ++j) {
    int s = (tid & 15) + 16 * j;       // 16 lanes of a ray -> consecutive dests
    bool bit = (msk >> s) & 1ull;
    int below = __popcll(msk & ((1ull << s) - 1ull));
    float dep = nr + f * ((float)s * DELTA);
    float sx = (ox + dx * dep) / R;
    float sy = (oy + dy * dep) / R;
    float sz = (oz + dz * dep) / R;
    float prev = (s == 0) ? nr : (nr + f * ((float)(s - 1) * DELTA));
    float del = dep - prev;
    int idxv = Vr - V0 + below;                       // rank among block valids
    int idxt = (r * S - Vr) - TV + (s - below);       // rank among block tails
    int i1 = bit ? idxv : idxt;
    buf[(bit ? Sv[0] : St[0]) + i1] = fr;
    int sb = (bit ? Sv[1] : St[1]) + 3 * i1;
    buf[sb] = sx; buf[sb + 1] = sy; buf[sb + 2] = sz;
    buf[(bit ? Sv[2] : St[2]) + i1] = dep;
    buf[(bit ? Sv[3] : St[3]) + i1] = del;
    buf[(bit ? Sv[4] : St[4]) + i1] = (bit && below == 0) ? 1.0f : 0.0f;
  }
  __syncthreads();

  // ---- streaming write phase: 10 runs, aligned float4 interiors ----
  size_t M = (size_t)N * S;
  auto wr = [&](int lds0, size_t g0, int cnt) {
    int a0 = (int)((4 - (g0 & 3)) & 3);
    if (a0 > cnt) a0 = cnt;
    int body = cnt - a0;
    int n4 = body >> 2, rem = body & 3;
    if (tid < a0) out[g0 + tid] = buf[lds0 + tid];
    int l0 = lds0 + a0;                 // multiple of 4 by construction
    for (int c = tid; c < n4; c += 256) {
      float4 v = *reinterpret_cast<const float4*>(&buf[l0 + 4 * c]);
      *reinterpret_cast<float4*>(out + g0 + a0 + 4 * (size_t)c) = v;
    }
    if (tid < rem) {
      int e = 4 * n4 + rem - 1 - tid;   // last few
      out[g0 + a0 + e] = buf[l0 + e];
    }
  };
  wr(Sv[0], (size_t)V0, cV);
  wr(St[0], tail0, cT);
  wr(Sv[1], M + 3 * (size_t)V0, 3 * cV);
  wr(St[1], M + 3 * tail0, 3 * cT);
  wr(Sv[2], 4 * M + (size_t)V0, cV);
  wr(St[2], 4 * M + tail0, cT);
  wr(Sv[3], 5 * M + (size_t)V0, cV);
  wr(St[3], 5 * M + tail0, cT);
  wr(Sv[4], 6 * M + (size_t)V0, cV);
  wr(St[4], 6 * M + tail0, cT);
}

}  // namespace

extern "C" void kernel_launch(void* const* d_in, const int* in_sizes, int n_in,
                              void* d_out, int out_size, void* d_ws, size_t ws_size,
                              hipStream_t stream) {
  const float* ro = (const float*)d_in[0];
  const float* rd = (const float*)d_in[1];
  const float* radii = (const float*)d_in[2];
  int N = in_sizes[0] / 3;           // 262144
  int M = N * S;                     // 16777216
  int nbA = (N + 255) / 256;         // 1024

  float4* rayinfo = (float4*)d_ws;             // N float4 (16B aligned)
  int* wsI = (int*)(rayinfo + N);
  int* L = wsI;                      // N ints
  int* blockSums = wsI + N;          // nbA ints
  int* blockOff = blockSums + nbA;   // nbA ints
  int* total = blockOff + nbA;       // 1 int

  float* out = (float*)d_out;
  float* out_nv = out + (size_t)7 * (size_t)M;  // num_valid slot

  k_count<<<nbA, 256, 0, stream>>>(ro, rd, radii, rayinfo, L, blockSums, N);
  k_scan<<<1, 1024, 0, stream>>>(blockSums, blockOff, total, out_nv, nbA);
  k_stage<<<N / RPB, 256, 0, stream>>>(ro, rd, radii, rayinfo, L, blockOff,
                                       total, out, N);
}

// Round 5
// 134.356 us; speedup vs baseline: 1.3905x; 1.0448x over previous
//
#include <hip/hip_runtime.h>

// Kill FMA contraction globally: the MASK (k_count) must match numpy/XLA's
// separate mul+add rounding bit-for-bit, or borderline mask bits flip and the
// whole compaction permutation shifts. k_stage uses explicit fmaf()/rcp-mul
// (output values only need absmax < ~4e-3, not bit-exactness).
#pragma clang fp contract(off)

namespace {

constexpr int S = 64;
// linspace(0,1,64): t_i = i * fl(1/63). fl(63*fl(1/63)) == 1.0f exactly.
constexpr float DELTA = 1.0f / 63.0f;

constexpr int RPB = 16;                   // rays per staging block
constexpr int Q = RPB * S;                // 1024 samples per block
constexpr int LQ = Q + 16;                // scalar-array LDS slot (pad for mod-4 shifts)
constexpr int SB = 4 * LQ;                // samples region base
constexpr int LDSF = SB + 3 * Q + 16;     // 7248 floats = 29.0 KB

__device__ __forceinline__ void ray_nearfar(
    float ox, float oy, float oz,
    float dx, float dy, float dz,
    float R, float& nr, float& fr) {
  float ix = 1.0f / ((dx == 0.0f) ? 1e-6f : dx);
  float iy = 1.0f / ((dy == 0.0f) ? 1e-6f : dy);
  float iz = 1.0f / ((dz == 0.0f) ? 1e-6f : dz);
  float mR = -R;
  float ax = (mR - ox) * ix, bx = (R - ox) * ix;
  float ay = (mR - oy) * iy, by = (R - oy) * iy;
  float az = (mR - oz) * iz, bz = (R - oz) * iz;
  nr = fmaxf(fmaxf(fminf(ax, bx), fminf(ay, by)), fminf(az, bz));
  fr = fminf(fminf(fmaxf(ax, bx), fmaxf(ay, by)), fmaxf(az, bz));
}

// Kernel A: one thread per ray. Compute near/f + 64-bit validity mask, persist
// them (float4: nr, f, mask_lo, mask_hi). Exclusive scan of counts in-block.
// sqrt-free mask: RN(sqrt(q)) <= 1.0  <=>  q <= 1+2^-23  (IEEE sqrt theorem;
// boundary floats checked: sqrt(1+2^-23) rounds to 1.0, sqrt(1+2^-22) to
// 1+2^-23). q itself is computed with np's exact op order, contract off.
__global__ __launch_bounds__(256) void k_count(
    const float* __restrict__ ro, const float* __restrict__ rd,
    const float* __restrict__ radii,
    float4* __restrict__ rayinfo,
    int* __restrict__ L, int* __restrict__ blockSums, int N) {
  int r = blockIdx.x * 256 + threadIdx.x;
  int cnt = 0;
  const float QLIM = __uint_as_float(0x3F800001u);  // 1 + 2^-23
  if (r < N) {
    float R = radii[0];
    float ox = ro[3 * r], oy = ro[3 * r + 1], oz = ro[3 * r + 2];
    float dx = rd[3 * r], dy = rd[3 * r + 1], dz = rd[3 * r + 2];
    float nr, fr;
    ray_nearfar(ox, oy, oz, dx, dy, dz, R, nr, fr);
    float f = fr - nr;
    unsigned lo = 0, hi = 0;
    for (int s = 0; s < S; ++s) {
      float dep = nr + f * ((float)s * DELTA);
      float sx = (ox + dx * dep) / R;
      float sy = (oy + dy * dep) / R;
      float sz = (oz + dz * dep) / R;
      float q = (sx * sx + sy * sy) + sz * sz;
      unsigned bit = (q <= QLIM) ? 1u : 0u;
      if (s < 32) lo |= bit << s; else hi |= bit << (s - 32);
      cnt += (int)bit;
    }
    rayinfo[r] = make_float4(nr, f, __uint_as_float(lo), __uint_as_float(hi));
  }
  __shared__ int sm[256];
  sm[threadIdx.x] = cnt;
  __syncthreads();
  for (int off = 1; off < 256; off <<= 1) {
    int t = (threadIdx.x >= off) ? sm[threadIdx.x - off] : 0;
    __syncthreads();
    sm[threadIdx.x] += t;
    __syncthreads();
  }
  if (r < N) L[r] = sm[threadIdx.x] - cnt;  // exclusive within block
  if (threadIdx.x == 255) blockSums[blockIdx.x] = sm[255];
}

// Kernel B: single block scans the (<=1024) block sums -> exclusive block
// offsets, total valid count (int to ws, float to d_out tail).
__global__ __launch_bounds__(1024) void k_scan(
    const int* __restrict__ blockSums, int* __restrict__ blockOff,
    int* __restrict__ total, float* __restrict__ out_nv, int nb) {
  __shared__ int sm[1024];
  int x = (threadIdx.x < nb) ? blockSums[threadIdx.x] : 0;
  sm[threadIdx.x] = x;
  __syncthreads();
  for (int off = 1; off < 1024; off <<= 1) {
    int t = (threadIdx.x >= off) ? sm[threadIdx.x - off] : 0;
    __syncthreads();
    sm[threadIdx.x] += t;
    __syncthreads();
  }
  if (threadIdx.x < nb) blockOff[threadIdx.x] = sm[threadIdx.x] - x;
  if (threadIdx.x == 1023) {
    *total = sm[1023];
    out_nv[0] = (float)sm[1023];
  }
}

// Kernel C: 16 rays per block. Block-local stable partition into LDS laid out
// congruent (mod 4 floats) with each run's global destination. The 4 scalar
// arrays (ridx/depth/deltas/boundary) share run geometry -> one fused loop
// does 4 ds_read_b128 + 4 dwordx4 stores per bounds check (LDS stride LQ as
// offset immediates). Values use fast math (fmaf + rcp-mul): tolerance 4e-3.
__global__ __launch_bounds__(256) void k_stage(
    const float* __restrict__ ro, const float* __restrict__ rd,
    const float* __restrict__ radii,
    const float4* __restrict__ rayinfo,
    const int* __restrict__ L, const int* __restrict__ blockOff,
    const int* __restrict__ total,
    float* __restrict__ out, int N) {
  __shared__ __align__(16) float buf[LDSF];
  int nwg = gridDim.x;                 // 16384, divisible by 8
  int chunk = nwg >> 3;
  int hw = blockIdx.x;
  int bid = (hw & 7) * chunk + (hw >> 3);   // XCD-chunked swizzle
  int r0 = bid * RPB;
  int tid = threadIdx.x;
  int nv = *total;
  int V0 = L[r0] + blockOff[r0 >> 8];
  int rB = r0 + RPB;
  int VB = (rB >= N) ? nv : (L[rB] + blockOff[rB >> 8]);
  int cV = VB - V0;                    // valid samples in this block
  int cT = Q - cV;
  int TV = r0 * S - V0;                // invalid samples before this block
  size_t tail0 = (size_t)nv + (size_t)TV;

  // LDS run bases, congruent mod 4 with global dests.
  int sv = V0 & 3;
  int st = ((sv + cV + 3) & ~3) + (int)(tail0 & 3);
  int svS = (3 * V0) & 3;
  int stS = ((svS + 3 * cV + 3) & ~3) + (int)((3 * tail0) & 3);

  // ---- compute + local stable partition into LDS ----
  int r = r0 + (tid >> 4);             // 16 threads per ray
  float R = radii[0];
  float invR = 1.0f / R;               // once; per-sample values use mul
  float4 info = rayinfo[r];
  float nr = info.x, f = info.y;
  unsigned long long msk =
      ((unsigned long long)__float_as_uint(info.w) << 32) |
      (unsigned long long)__float_as_uint(info.z);
  float ox = ro[3 * r], oy = ro[3 * r + 1], oz = ro[3 * r + 2];
  float dx = rd[3 * r], dy = rd[3 * r + 1], dz = rd[3 * r + 2];
  int Vr = L[r] + blockOff[r >> 8];
  float fridx = (float)r;
  int idxvB = Vr - V0;                 // block-local valid base for this ray
  int idxtB = (r * S - Vr) - TV;       // block-local tail base for this ray
  #pragma unroll
  for (int j = 0; j < 4; ++j) {
    int s = (tid & 15) + 16 * j;       // 16 lanes of a ray -> consecutive dests
    bool bit = (msk >> s) & 1ull;
    int below = __popcll(msk & ((1ull << s) - 1ull));
    float dep = fmaf(f, (float)s * DELTA, nr);
    float sx = fmaf(dx, dep, ox) * invR;
    float sy = fmaf(dy, dep, oy) * invR;
    float sz = fmaf(dz, dep, oz) * invR;
    float prev = fmaf(f, (float)(s - 1) * DELTA, nr);
    float del = s ? (dep - prev) : 0.0f;
    int i1 = bit ? (idxvB + below) : (idxtB + (s - below));
    int b0 = (bit ? sv : st) + i1;
    buf[b0] = fridx;                   // ridx      (slot 0)
    buf[b0 + LQ] = dep;                // depth     (slot 1)
    buf[b0 + 2 * LQ] = del;            // deltas    (slot 2)
    buf[b0 + 3 * LQ] = (bit && below == 0) ? 1.0f : 0.0f;  // boundary (slot 3)
    int b1 = SB + (bit ? svS : stS) + 3 * i1;
    buf[b1] = sx; buf[b1 + 1] = sy; buf[b1 + 2] = sz;
  }
  __syncthreads();

  // ---- streaming write phase ----
  size_t M = (size_t)N * S;
  // global bases of the 4 scalar arrays: ridx 0, depth 4M, deltas 5M, bnd 6M
  const size_t A1 = 4 * M, A2 = 5 * M, A3 = 6 * M;

  // fused scalar runs (valid then tail)
  {
    int a0 = (-V0) & 3; if (a0 > cV) a0 = cV;
    int body = cV - a0, n4 = body >> 2, rem = body & 3;
    int l0 = sv + a0;                  // multiple of 4
    size_t g = (size_t)V0 + a0;
    for (int c = tid; c < n4; c += 256) {
      int l = l0 + 4 * c; size_t gg = g + 4 * (size_t)c;
      *(float4*)(out + gg)      = *(const float4*)&buf[l];
      *(float4*)(out + A1 + gg) = *(const float4*)&buf[l + LQ];
      *(float4*)(out + A2 + gg) = *(const float4*)&buf[l + 2 * LQ];
      *(float4*)(out + A3 + gg) = *(const float4*)&buf[l + 3 * LQ];
    }
    if (tid < a0) {
      size_t gg = (size_t)V0 + tid; int l = sv + tid;
      out[gg] = buf[l]; out[A1 + gg] = buf[l + LQ];
      out[A2 + gg] = buf[l + 2 * LQ]; out[A3 + gg] = buf[l + 3 * LQ];
    }
    if (tid < rem) {
      int e = a0 + 4 * n4 + tid;
      size_t gg = (size_t)V0 + e; int l = sv + e;
      out[gg] = buf[l]; out[A1 + gg] = buf[l + LQ];
      out[A2 + gg] = buf[l + 2 * LQ]; out[A3 + gg] = buf[l + 3 * LQ];
    }
  }
  {
    int a0 = (int)((-tail0) & 3); if (a0 > cT) a0 = cT;
    int body = cT - a0, n4 = body >> 2, rem = body & 3;
    int l0 = st + a0;
    size_t g = tail0 + a0;
    for (int c = tid; c < n4; c += 256) {
      int l = l0 + 4 * c; size_t gg = g + 4 * (size_t)c;
      *(float4*)(out + gg)      = *(const float4*)&buf[l];
      *(float4*)(out + A1 + gg) = *(const float4*)&buf[l + LQ];
      *(float4*)(out + A2 + gg) = *(const float4*)&buf[l + 2 * LQ];
      *(float4*)(out + A3 + gg) = *(const float4*)&buf[l + 3 * LQ];
    }
    if (tid < a0) {
      size_t gg = tail0 + tid; int l = st + tid;
      out[gg] = buf[l]; out[A1 + gg] = buf[l + LQ];
      out[A2 + gg] = buf[l + 2 * LQ]; out[A3 + gg] = buf[l + 3 * LQ];
    }
    if (tid < rem) {
      int e = a0 + 4 * n4 + tid;
      size_t gg = tail0 + e; int l = st + e;
      out[gg] = buf[l]; out[A1 + gg] = buf[l + LQ];
      out[A2 + gg] = buf[l + 2 * LQ]; out[A3 + gg] = buf[l + 3 * LQ];
    }
  }
  // samples runs (scale 3)
  {
    size_t g0 = M + 3 * (size_t)V0; int cnt = 3 * cV;
    int a0 = (int)((-g0) & 3); if (a0 > cnt) a0 = cnt;
    int body = cnt - a0, n4 = body >> 2, rem = body & 3;
    int l0 = SB + svS + a0;
    for (int c = tid; c < n4; c += 256)
      *(float4*)(out + g0 + a0 + 4 * (size_t)c) = *(const float4*)&buf[l0 + 4 * c];
    if (tid < a0) out[g0 + tid] = buf[SB + svS + tid];
    if (tid < rem) { int e = a0 + 4 * n4 + tid; out[g0 + e] = buf[SB + svS + e]; }
  }
  {
    size_t g0 = M + 3 * tail0; int cnt = 3 * cT;
    int a0 = (int)((-g0) & 3); if (a0 > cnt) a0 = cnt;
    int body = cnt - a0, n4 = body >> 2, rem = body & 3;
    int l0 = SB + stS + a0;
    for (int c = tid; c < n4; c += 256)
      *(float4*)(out + g0 + a0 + 4 * (size_t)c) = *(const float4*)&buf[l0 + 4 * c];
    if (tid < a0) out[g0 + tid] = buf[SB + stS + tid];
    if (tid < rem) { int e = a0 + 4 * n4 + tid; out[g0 + e] = buf[SB + stS + e]; }
  }
}

}  // namespace

extern "C" void kernel_launch(void* const* d_in, const int* in_sizes, int n_in,
                              void* d_out, int out_size, void* d_ws, size_t ws_size,
                              hipStream_t stream) {
  const float* ro = (const float*)d_in[0];
  const float* rd = (const float*)d_in[1];
  const float* radii = (const float*)d_in[2];
  int N = in_sizes[0] / 3;           // 262144
  int M = N * S;                     // 16777216
  int nbA = (N + 255) / 256;         // 1024

  float4* rayinfo = (float4*)d_ws;             // N float4 (16B aligned)
  int* wsI = (int*)(rayinfo + N);
  int* L = wsI;                      // N ints
  int* blockSums = wsI + N;          // nbA ints
  int* blockOff = blockSums + nbA;   // nbA ints
  int* total = blockOff + nbA;       // 1 int

  float* out = (float*)d_out;
  float* out_nv = out + (size_t)7 * (size_t)M;  // num_valid slot

  k_count<<<nbA, 256, 0, stream>>>(ro, rd, radii, rayinfo, L, blockSums, N);
  k_scan<<<1, 1024, 0, stream>>>(blockSums, blockOff, total, out_nv, nbA);
  k_stage<<<N / RPB, 256, 0, stream>>>(ro, rd, radii, rayinfo, L, blockOff,
                                       total, out, N);
}